// Round 9
// baseline (70.973 us; speedup 1.0000x reference)
//
#include <hip/hip_runtime.h>
#include <hip/hip_bf16.h>
#include <math.h>

#define N 2048
#define CIN 128
#define COUT 64
#define NEG 0.2f
#define NSLAB 16     // 128-row i-slabs
#define NJBLK 32     // 64-row j-blocks

typedef __attribute__((ext_vector_type(8))) short short8;   // 8 bf16
typedef __attribute__((ext_vector_type(4))) float f32x4;

__device__ __forceinline__ short bf16bits(float x) {
  __hip_bfloat16 b = __float2bfloat16(x);
  return *reinterpret_cast<short*>(&b);
}

// Kernel 1: h = data @ W; a_s = h@att_src; a_d = h@att_dst; zero cnt[].
// h stored ONLY as bf16 in MFMA B-fragment order (frame f = (i>>5)*4 + (c>>4),
// lane L = ((i>>3)&3)*16 + (c&15), elem e = i&7).
__global__ __launch_bounds__(64) void gat_gemm(
    const float* __restrict__ data, const float* __restrict__ W,
    const float* __restrict__ att_src, const float* __restrict__ att_dst,
    ushort* __restrict__ hfrag, float* __restrict__ a_s,
    float* __restrict__ a_d, int* __restrict__ cnt) {
  const int row = blockIdx.x;
  const int c = threadIdx.x;

  if (row < NJBLK && c == 0) cnt[row] = 0;  // completion counters for node 2

  __shared__ float drow[CIN];
  drow[c]      = data[row * CIN + c];
  drow[c + 64] = data[row * CIN + 64 + c];
  __syncthreads();

  float a0 = 0.f, a1 = 0.f, a2 = 0.f, a3 = 0.f;
#pragma unroll
  for (int k = 0; k < CIN; k += 4) {
    a0 = fmaf(drow[k],     W[(k)     * COUT + c], a0);
    a1 = fmaf(drow[k + 1], W[(k + 1) * COUT + c], a1);
    a2 = fmaf(drow[k + 2], W[(k + 2) * COUT + c], a2);
    a3 = fmaf(drow[k + 3], W[(k + 3) * COUT + c], a3);
  }
  const float acc = (a0 + a1) + (a2 + a3);

  {
    const int L = ((row >> 3) & 3) * 16 + (c & 15);
    const int e = row & 7;
    const int f = (row >> 5) * 4 + (c >> 4);
    hfrag[((size_t)(f * 64 + L) << 3) + e] = (ushort)bf16bits(acc);
  }

  float s = acc * att_src[c];
  float d = acc * att_dst[c];
#pragma unroll
  for (int o = 32; o; o >>= 1) {
    s += __shfl_xor(s, o);
    d += __shfl_xor(d, o);
  }
  if (c == 0) { a_s[row] = s; a_d[row] = d; }
}

// Kernel 2: MFMA attention tiles + fused finalize (threadFenceReduction).
// Block (bj, ph) computes a 64j x 128i tile (16 MFMA, no LDS in main path,
// no barriers until the epilogue). Last-finishing block per bj sums the
// fixed-slot partials in fixed order (deterministic) and writes out.
__global__ __launch_bounds__(256) void gat_attn_mfma(
    const ushort* __restrict__ hfrag, const float* __restrict__ a_s,
    const float* __restrict__ a_d, const float* __restrict__ bias,
    float* __restrict__ part, float* __restrict__ denp,
    int* __restrict__ cnt, float* __restrict__ out) {
  const int bj = (int)blockIdx.x;       // j-block 0..31
  const int ph = (int)blockIdx.y;       // i-slab 0..15
  const int ns = (bj >> 1) + 1;         // i-slabs contributing to this bj
  if (ph >= ns) return;                 // dead tile (strictly upper)

  const int tid = (int)threadIdx.x;
  const int wid = tid >> 6;
  const int lane = tid & 63;
  const int j0w = bj * 64 + wid * 16;
  const int jme = j0w + (lane & 15);    // this lane's A-frag j-row
  const int kgrp = lane >> 4;           // k-chunk 0..3
  const float ad_me = a_d[jme];

  f32x4 acc0 = {0.f, 0.f, 0.f, 0.f};
  f32x4 acc1 = acc0, acc2 = acc0, acc3 = acc0;
  float dsum = 0.f;
  const uint4* hf = (const uint4*)hfrag;

#pragma unroll
  for (int ks = 0; ks < 4; ++ks) {
    const int ibase = ph * 128 + ks * 32 + kgrp * 8;
    const float4 asa = *(const float4*)&a_s[ibase];
    const float4 asb = *(const float4*)&a_s[ibase + 4];
    const float av[8] = {asa.x, asa.y, asa.z, asa.w,
                         asb.x, asb.y, asb.z, asb.w};
    short8 af;
#pragma unroll
    for (int e = 0; e < 8; ++e) {
      float x = av[e] + ad_me;
      x = fmaxf(x, NEG * x);                 // leaky_relu
      float w = __expf(x);                   // no max-shift (logits bounded)
      if (ibase + e > jme) w = 0.f;          // causal mask i <= j
      dsum += w;
      af[e] = bf16bits(w);
    }
    const int fbase = ((ph * 4 + ks) * 4) * 64 + lane;
    const uint4 b0 = hf[fbase];
    const uint4 b1 = hf[fbase + 64];
    const uint4 b2 = hf[fbase + 128];
    const uint4 b3 = hf[fbase + 192];
    acc0 = __builtin_amdgcn_mfma_f32_16x16x32_bf16(af, *(const short8*)&b0,
                                                   acc0, 0, 0, 0);
    acc1 = __builtin_amdgcn_mfma_f32_16x16x32_bf16(af, *(const short8*)&b1,
                                                   acc1, 0, 0, 0);
    acc2 = __builtin_amdgcn_mfma_f32_16x16x32_bf16(af, *(const short8*)&b2,
                                                   acc2, 0, 0, 0);
    acc3 = __builtin_amdgcn_mfma_f32_16x16x32_bf16(af, *(const short8*)&b3,
                                                   acc3, 0, 0, 0);
  }

  // den partial: reduce over the 4 k-chunks
  dsum += __shfl_xor(dsum, 16);
  dsum += __shfl_xor(dsum, 32);
  if ((lane & 48) == 0) denp[ph * N + j0w + lane] = dsum;

  // num partials (C/D layout: col=lane&15, row=kgrp*4+reg)
  {
    float* pb = part + (size_t)ph * (N * COUT) + (size_t)j0w * COUT;
#pragma unroll
    for (int r = 0; r < 4; ++r) {
      const int jr = (kgrp * 4 + r) * COUT + (lane & 15);
      pb[jr]      = acc0[r];
      pb[jr + 16] = acc1[r];
      pb[jr + 32] = acc2[r];
      pb[jr + 48] = acc3[r];
    }
  }

  // ---- completion protocol: last block for bj finalizes ----
  __shared__ int lastFlag;
  __shared__ float dtot[64];
  __syncthreads();
  __threadfence();  // make this block's stores device-visible
  if (tid == 0) lastFlag = (atomicAdd(&cnt[bj], 1) == ns - 1);
  __syncthreads();
  if (!lastFlag) return;
  __threadfence();  // acquire: other blocks' stores now visible

  if (tid < 64) {
    float den = 0.f;
    for (int s = 0; s < ns; ++s) den += denp[s * N + bj * 64 + tid];
    dtot[tid] = den;
  }
  __syncthreads();
#pragma unroll
  for (int e = 0; e < 16; ++e) {
    const int idx = e * 256 + tid;           // 0..4095 within the j-block
    const int j = idx >> 6, c = idx & 63;
    const size_t gidx = (size_t)(bj * 64 + j) * COUT + c;
    float num = 0.f;
    for (int s = 0; s < ns; ++s) num += part[(size_t)s * (N * COUT) + gidx];
    const float v = num / dtot[j] + bias[c];
    out[gidx] = v > 0.f ? v : 0.f;
  }
}

extern "C" void kernel_launch(void* const* d_in, const int* in_sizes, int n_in,
                              void* d_out, int out_size, void* d_ws, size_t ws_size,
                              hipStream_t stream) {
  const float* data    = (const float*)d_in[0];  // [N, CIN]
  const float* W       = (const float*)d_in[1];  // [CIN, COUT]
  const float* att_src = (const float*)d_in[2];  // [COUT]
  const float* att_dst = (const float*)d_in[3];  // [COUT]
  const float* bias    = (const float*)d_in[4];  // [COUT]
  float* out = (float*)d_out;                    // [N, COUT]

  ushort* hfrag = (ushort*)d_ws;                 // N*COUT bf16 (256KB)
  float* a_s  = (float*)d_ws + 65536;            // N
  float* a_d  = a_s + N;                         // N
  float* part = a_d + N;                         // NSLAB*N*COUT (8MB)
  float* denp = part + (size_t)NSLAB * N * COUT; // NSLAB*N
  int*   cnt  = (int*)(denp + NSLAB * N);        // NJBLK ints

  gat_gemm<<<N, 64, 0, stream>>>(data, W, att_src, att_dst, hfrag, a_s, a_d,
                                 cnt);
  gat_attn_mfma<<<dim3(NJBLK, NSLAB), 256, 0, stream>>>(hfrag, a_s, a_d, bias,
                                                        part, denp, cnt, out);
}